// Round 1
// baseline (1181.749 us; speedup 1.0000x reference)
//
#include <hip/hip_runtime.h>

#define HID 64
#define NBLK 8

// One thread = one point. h/h2 kept in registers via full unroll (static
// indices only — runtime-indexed register arrays spill to scratch).
// Weight reads are wave-uniform -> scalar loads through the scalar cache.
__global__ __launch_bounds__(256) void cinn_f32_kernel(
    const float* __restrict__ q_feat,   // (N,4)
    const float* __restrict__ Hc,       // (N,2)
    const float* __restrict__ W1,       // (8,64,4)
    const float* __restrict__ b1,       // (8,64)
    const float* __restrict__ W2,       // (8,64,64)
    const float* __restrict__ b2,       // (8,64)
    const float* __restrict__ W3,       // (8,4,64)
    const float* __restrict__ b3,       // (8,4)
    const float* __restrict__ w_perm,   // (8,4,4)
    const float* __restrict__ g_scale,  // (8,4)
    const float* __restrict__ g_offset, // (8,4)
    float* __restrict__ out_x,          // (N,4)
    float* __restrict__ out_ld,         // (N,)
    int n)
{
  // Per-block uniform transcendentals computed once per workgroup.
  __shared__ float s_scale[NBLK][4];
  __shared__ float s_logsum[NBLK];
  if (threadIdx.x < NBLK) {
    int i = threadIdx.x;
    float ls = 0.f;
    for (int d = 0; d < 4; ++d) {
      float gs = g_scale[i * 4 + d];
      float sc = 0.2f * log1pf(expf(0.5f * gs));
      s_scale[i][d] = sc;
      ls += logf(sc);
    }
    s_logsum[i] = ls;
  }
  __syncthreads();

  int pt = blockIdx.x * blockDim.x + threadIdx.x;
  if (pt >= n) return;

  float4 xv = *reinterpret_cast<const float4*>(q_feat + (size_t)pt * 4);
  float x0 = xv.x, x1 = xv.y, x2 = xv.z, x3 = xv.w;
  float2 hv = *reinterpret_cast<const float2*>(Hc + (size_t)pt * 2);
  float c0 = hv.x, c1 = hv.y;
  float logdet = 0.f;

  for (int i = 0; i < NBLK; ++i) {
    const float* W1i = W1 + i * HID * 4;
    const float* b1i = b1 + i * HID;
    const float* W2i = W2 + i * HID * HID;
    const float* b2i = b2 + i * HID;
    const float* W3i = W3 + i * 4 * HID;
    const float* b3i = b3 + i * 4;
    const float* wpi = w_perm + i * 16;
    const float* goi = g_offset + i * 4;

    // layer 1: (x0,x1,c0,c1) @ W1^T + b1, relu
    float h[HID];
#pragma unroll
    for (int j = 0; j < HID; ++j) {
      float acc = b1i[j];
      acc = fmaf(W1i[j * 4 + 0], x0, acc);
      acc = fmaf(W1i[j * 4 + 1], x1, acc);
      acc = fmaf(W1i[j * 4 + 2], c0, acc);
      acc = fmaf(W1i[j * 4 + 3], c1, acc);
      h[j] = fmaxf(acc, 0.f);
    }
    // layer 2: h @ W2^T + b2, relu  (the 4096-MAC hot loop)
    float h2[HID];
#pragma unroll
    for (int j = 0; j < HID; ++j) {
      float acc = b2i[j];
#pragma unroll
      for (int k = 0; k < HID; ++k)
        acc = fmaf(W2i[j * HID + k], h[k], acc);
      h2[j] = fmaxf(acc, 0.f);
    }
    // layer 3: h2 @ W3^T + b3, *0.1
    float a[4];
#pragma unroll
    for (int j = 0; j < 4; ++j) {
      float acc = b3i[j];
#pragma unroll
      for (int k = 0; k < HID; ++k)
        acc = fmaf(W3i[j * HID + k], h2[k], acc);
      a[j] = acc * 0.1f;
    }
    // coupling
    float s0 = 2.f * tanhf(a[0]);
    float s1 = 2.f * tanhf(a[1]);
    x2 = x2 * expf(s0) + a[2];
    x3 = x3 * expf(s1) + a[3];
    logdet += s0 + s1 + s_logsum[i];

    // actnorm + permutation
    float sc0 = s_scale[i][0], sc1 = s_scale[i][1];
    float sc2 = s_scale[i][2], sc3 = s_scale[i][3];
    float y0 = fmaf(x0, sc0, goi[0]);
    float y1 = fmaf(x1, sc1, goi[1]);
    float y2 = fmaf(x2, sc2, goi[2]);
    float y3 = fmaf(x3, sc3, goi[3]);
    float nx0 = wpi[0] * y0 + wpi[1] * y1 + wpi[2] * y2 + wpi[3] * y3;
    float nx1 = wpi[4] * y0 + wpi[5] * y1 + wpi[6] * y2 + wpi[7] * y3;
    float nx2 = wpi[8] * y0 + wpi[9] * y1 + wpi[10] * y2 + wpi[11] * y3;
    float nx3 = wpi[12] * y0 + wpi[13] * y1 + wpi[14] * y2 + wpi[15] * y3;
    x0 = nx0; x1 = nx1; x2 = nx2; x3 = nx3;
  }

  *reinterpret_cast<float4*>(out_x + (size_t)pt * 4) = make_float4(x0, x1, x2, x3);
  out_ld[pt] = logdet;
}

extern "C" void kernel_launch(void* const* d_in, const int* in_sizes, int n_in,
                              void* d_out, int out_size, void* d_ws, size_t ws_size,
                              hipStream_t stream) {
  const float* q_feat   = (const float*)d_in[0];
  const float* Hc       = (const float*)d_in[1];
  const float* W1       = (const float*)d_in[2];
  const float* b1       = (const float*)d_in[3];
  const float* W2       = (const float*)d_in[4];
  const float* b2       = (const float*)d_in[5];
  const float* W3       = (const float*)d_in[6];
  const float* b3       = (const float*)d_in[7];
  const float* w_perm   = (const float*)d_in[8];
  const float* g_scale  = (const float*)d_in[9];
  const float* g_offset = (const float*)d_in[10];

  int n = in_sizes[0] / 4;
  float* out_x  = (float*)d_out;
  float* out_ld = out_x + (size_t)n * 4;

  int blocks = (n + 255) / 256;
  hipLaunchKernelGGL(cinn_f32_kernel, dim3(blocks), dim3(256), 0, stream,
                     q_feat, Hc, W1, b1, W2, b2, W3, b3, w_perm, g_scale,
                     g_offset, out_x, out_ld, n);
}

// Round 3
// 430.147 us; speedup vs baseline: 2.7473x; 2.7473x over previous
//
#include <hip/hip_runtime.h>

typedef _Float16 f16;
typedef _Float16 f16x8 __attribute__((ext_vector_type(8)));
typedef float f32x4 __attribute__((ext_vector_type(4)));

#define NBLK 8
#define MFMA(a, b, c) __builtin_amdgcn_mfma_f32_16x16x32_f16(a, b, c, 0, 0, 0)

// Consumer-side K position k -> producer-side slot feature index.
// Producer D slot (t,g,r) holds feature m=16t+4g+r at the register position the
// next layer's B operand reads as k=32s+8g+e (see make_b repack).
__device__ __forceinline__ int pinv(int k) {
  return 16 * (2 * (k >> 5) + ((k >> 2) & 1)) + 4 * ((k >> 3) & 3) + (k & 3);
}
__device__ __forceinline__ float hi_part(float v) { return (float)(f16)v; }
__device__ __forceinline__ float lo_part(float v) { f16 h = (f16)v; return v - (float)h; }

// One-time weight prep: writes fragment-layout f16 images to ws.
// Per block i: img 0..3   A1[t]   (K-slots: 0-3 W1hi, 4-7 W1lo, 8-11 W1hi, 12/13 b1 hi/lo)
//              img 4..11  A2hi[t*2+s], img 12..19 A2lo[t*2+s]
//              img 20,21  A3hi[s],     img 22,23  A3lo[s]
// Image layout: [lane][e] contiguous -> main kernel reads one dwordx4 per lane.
__global__ void prep_weights(const float* __restrict__ W1, const float* __restrict__ b1,
                             const float* __restrict__ W2, const float* __restrict__ W3,
                             f16* __restrict__ wsp) {
  int i = blockIdx.x / 24;
  int img = blockIdx.x % 24;
  int lane = threadIdx.x;
  int c = lane & 15, g = lane >> 4;
  f16 vals[8];
#pragma unroll
  for (int e = 0; e < 8; ++e) {
    float out = 0.f;
    if (img < 4) {
      int t = img, m = 16 * t + c, k = 8 * g + e;
      if (k < 4)       out = hi_part(W1[i * 256 + m * 4 + k]);
      else if (k < 8)  out = lo_part(W1[i * 256 + m * 4 + (k - 4)]);
      else if (k < 12) out = lo_part(W1[i * 256 + m * 4 + (k - 8)]);  // placeholder, fixed below
      else if (k == 12) out = hi_part(b1[i * 64 + m]);
      else if (k == 13) out = lo_part(b1[i * 64 + m]);
      else out = 0.f;
      // k in 8..11 must be W1 HI (pairs x-lo): overwrite correctly
      if (k >= 8 && k < 12) out = hi_part(W1[i * 256 + m * 4 + (k - 8)]);
    } else if (img < 20) {
      bool isLo = (img >= 12);
      int q = isLo ? (img - 12) : (img - 4);
      int t = q >> 1, s = q & 1, m = 16 * t + c;
      int k = 32 * s + 8 * g + e;
      float v = W2[i * 4096 + m * 64 + pinv(k)];
      out = isLo ? lo_part(v) : hi_part(v);
    } else {
      bool isLo = (img >= 22);
      int s = isLo ? (img - 22) : (img - 20);
      int k = 32 * s + 8 * g + e;
      float v = (c < 4) ? W3[i * 256 + c * 64 + pinv(k)] : 0.f;
      out = isLo ? lo_part(v) : hi_part(v);
    }
    vals[e] = (f16)out;
  }
  f16x8 vv = {vals[0], vals[1], vals[2], vals[3], vals[4], vals[5], vals[6], vals[7]};
  *(f16x8*)(wsp + ((size_t)i * 24 + img) * 512 + (size_t)lane * 8) = vv;
}

// D (4 tiles of f32x4) -> relu -> split-f16 B fragments (hi/lo), register-local.
// Scalar casts only (RNE); compiler packs.
__device__ __forceinline__ void make_b(const f32x4 d[4], f16x8 bh[2], f16x8 bl[2]) {
#pragma unroll
  for (int s = 0; s < 2; ++s) {
    float hr[8];
#pragma unroll
    for (int e = 0; e < 4; ++e) hr[e] = fmaxf(d[2 * s][e], 0.f);
#pragma unroll
    for (int e = 0; e < 4; ++e) hr[4 + e] = fmaxf(d[2 * s + 1][e], 0.f);
    f16 hh[8];
    f16 hl[8];
#pragma unroll
    for (int e = 0; e < 8; ++e) {
      hh[e] = (f16)hr[e];
      hl[e] = (f16)(hr[e] - (float)hh[e]);
    }
    bh[s] = (f16x8){hh[0], hh[1], hh[2], hh[3], hh[4], hh[5], hh[6], hh[7]};
    bl[s] = (f16x8){hl[0], hl[1], hl[2], hl[3], hl[4], hl[5], hl[6], hl[7]};
  }
}

__global__ __launch_bounds__(256) void cinn_mfma_kernel(
    const float* __restrict__ q_feat, const float* __restrict__ Hc,
    const float* __restrict__ b2, const float* __restrict__ b3,
    const float* __restrict__ w_perm, const float* __restrict__ g_scale,
    const float* __restrict__ g_offset, const f16* __restrict__ wf,
    float* __restrict__ out_x, float* __restrict__ out_ld, int n) {
  __shared__ float s_scale[NBLK][4];
  __shared__ float s_logsum[NBLK];
  if (threadIdx.x < NBLK) {
    int i = threadIdx.x;
    float ls = 0.f;
    for (int d = 0; d < 4; ++d) {
      float gs = g_scale[i * 4 + d];
      float sc = 0.2f * log1pf(expf(0.5f * gs));
      s_scale[i][d] = sc;
      ls += logf(sc);
    }
    s_logsum[i] = ls;
  }
  __syncthreads();

  int lane = threadIdx.x & 63;
  int c = lane & 15, g = lane >> 4;
  int wave = (blockIdx.x * blockDim.x + threadIdx.x) >> 6;
  int pt = wave * 16 + c;
  if (pt >= n) pt = n - 1;  // no early return: MFMA needs all 64 lanes

  float4 xv = *reinterpret_cast<const float4*>(q_feat + (size_t)pt * 4);
  float x0 = xv.x, x1 = xv.y, x2 = xv.z, x3 = xv.w;
  float2 hv = *reinterpret_cast<const float2*>(Hc + (size_t)pt * 2);
  float h0 = hv.x, h1 = hv.y;
  float logdet = 0.f;

  // Loop-invariant conditioner hi/lo
  f16 ch0 = (f16)h0, ch1 = (f16)h1;
  f16 cl0 = (f16)(h0 - (float)ch0), cl1 = (f16)(h1 - (float)ch1);
  const f16 fz = (f16)0, fone = (f16)1;
  const f32x4 zero4 = {0.f, 0.f, 0.f, 0.f};

#pragma unroll 1
  for (int i = 0; i < NBLK; ++i) {
    const f16* wb = wf + (size_t)i * 24 * 512 + (size_t)lane * 8;
    // B1 per K-slot (k = 8g+e):
    //  g=0: e0-3 = x1c hi (pairs W1hi), e4-7 = x1c hi (pairs W1lo)
    //  g=1: e0-3 = x1c lo (pairs W1hi), e4,5 = 1 (biases), e6,7 = 0
    //  g>=2: 0
    f16 xh0 = (f16)x0, xh1 = (f16)x1;
    f16 xl0 = (f16)(x0 - (float)xh0), xl1 = (f16)(x1 - (float)xh1);
    f16 B1e0 = (g == 0) ? xh0 : ((g == 1) ? xl0 : fz);
    f16 B1e1 = (g == 0) ? xh1 : ((g == 1) ? xl1 : fz);
    f16 B1e2 = (g == 0) ? ch0 : ((g == 1) ? cl0 : fz);
    f16 B1e3 = (g == 0) ? ch1 : ((g == 1) ? cl1 : fz);
    f16 B1e4 = (g == 0) ? xh0 : ((g == 1) ? fone : fz);
    f16 B1e5 = (g == 0) ? xh1 : ((g == 1) ? fone : fz);
    f16 B1e6 = (g == 0) ? ch0 : fz;
    f16 B1e7 = (g == 0) ? ch1 : fz;
    f16x8 B1 = {B1e0, B1e1, B1e2, B1e3, B1e4, B1e5, B1e6, B1e7};

    // L1 (split terms + bias folded into K-slots)
    f32x4 d1[4];
#pragma unroll
    for (int t = 0; t < 4; ++t) {
      f16x8 a = *(const f16x8*)(wb + t * 512);
      d1[t] = MFMA(a, B1, zero4);
    }
    f16x8 b2h[2], b2l[2];
    make_b(d1, b2h, b2l);

    // L2: hi*hi + lo*hi + hi*lo
    f32x4 d2[4];
#pragma unroll
    for (int t = 0; t < 4; ++t) {
      f32x4 acc = zero4;
#pragma unroll
      for (int s = 0; s < 2; ++s) {
        f16x8 ah = *(const f16x8*)(wb + (4 + 2 * t + s) * 512);
        f16x8 al = *(const f16x8*)(wb + (12 + 2 * t + s) * 512);
        acc = MFMA(ah, b2h[s], acc);
        acc = MFMA(al, b2h[s], acc);
        acc = MFMA(ah, b2l[s], acc);
      }
      const float4 bv = *reinterpret_cast<const float4*>(b2 + i * 64 + 16 * t + 4 * g);
      acc[0] += bv.x; acc[1] += bv.y; acc[2] += bv.z; acc[3] += bv.w;
      d2[t] = acc;
    }
    f16x8 b3h[2], b3l[2];
    make_b(d2, b3h, b3l);

    // L3
    f32x4 d3 = zero4;
#pragma unroll
    for (int s = 0; s < 2; ++s) {
      f16x8 ah = *(const f16x8*)(wb + (20 + s) * 512);
      f16x8 al = *(const f16x8*)(wb + (22 + s) * 512);
      d3 = MFMA(ah, b3h[s], d3);
      d3 = MFMA(al, b3h[s], d3);
      d3 = MFMA(ah, b3l[s], d3);
    }

    // a-values live on g=0 lanes (rows 0-3, col=point); broadcast so every
    // lane keeps the true x-state (g=1 lanes feed the x-lo fragment).
    float a0  = (__shfl(d3[0], c, 64) + b3[i * 4 + 0]) * 0.1f;
    float a1  = (__shfl(d3[1], c, 64) + b3[i * 4 + 1]) * 0.1f;
    float a2v = (__shfl(d3[2], c, 64) + b3[i * 4 + 2]) * 0.1f;
    float a3v = (__shfl(d3[3], c, 64) + b3[i * 4 + 3]) * 0.1f;
    float s0 = 2.f * tanhf(a0), s1 = 2.f * tanhf(a1);
    x2 = x2 * expf(s0) + a2v;
    x3 = x3 * expf(s1) + a3v;
    logdet += s0 + s1 + s_logsum[i];

    // actnorm + permutation (exact f32)
    float y0 = fmaf(x0, s_scale[i][0], g_offset[i * 4 + 0]);
    float y1 = fmaf(x1, s_scale[i][1], g_offset[i * 4 + 1]);
    float y2 = fmaf(x2, s_scale[i][2], g_offset[i * 4 + 2]);
    float y3 = fmaf(x3, s_scale[i][3], g_offset[i * 4 + 3]);
    const float* wp = w_perm + i * 16;
    float nx0 = wp[0] * y0 + wp[1] * y1 + wp[2] * y2 + wp[3] * y3;
    float nx1 = wp[4] * y0 + wp[5] * y1 + wp[6] * y2 + wp[7] * y3;
    float nx2 = wp[8] * y0 + wp[9] * y1 + wp[10] * y2 + wp[11] * y3;
    float nx3 = wp[12] * y0 + wp[13] * y1 + wp[14] * y2 + wp[15] * y3;
    x0 = nx0; x1 = nx1; x2 = nx2; x3 = nx3;
  }

  if (lane < 16) {
    *reinterpret_cast<float4*>(out_x + (size_t)pt * 4) = make_float4(x0, x1, x2, x3);
    out_ld[pt] = logdet;
  }
}

extern "C" void kernel_launch(void* const* d_in, const int* in_sizes, int n_in,
                              void* d_out, int out_size, void* d_ws, size_t ws_size,
                              hipStream_t stream) {
  const float* q_feat   = (const float*)d_in[0];
  const float* Hc       = (const float*)d_in[1];
  const float* W1       = (const float*)d_in[2];
  const float* b1       = (const float*)d_in[3];
  const float* W2       = (const float*)d_in[4];
  const float* b2       = (const float*)d_in[5];
  const float* W3       = (const float*)d_in[6];
  const float* b3       = (const float*)d_in[7];
  const float* w_perm   = (const float*)d_in[8];
  const float* g_scale  = (const float*)d_in[9];
  const float* g_offset = (const float*)d_in[10];

  int n = in_sizes[0] / 4;
  float* out_x  = (float*)d_out;
  float* out_ld = out_x + (size_t)n * 4;
  f16* wf = (f16*)d_ws;  // needs 8*24*512*2 = 196608 bytes

  hipLaunchKernelGGL(prep_weights, dim3(NBLK * 24), dim3(64), 0, stream,
                     W1, b1, W2, W3, wf);
  int blocks = (n + 63) / 64;  // 64 points per 256-thread block (16/wave)
  hipLaunchKernelGGL(cinn_mfma_kernel, dim3(blocks), dim3(256), 0, stream,
                     q_feat, Hc, b2, b3, w_perm, g_scale, g_offset, wf,
                     out_x, out_ld, n);
}